// Round 9
// baseline (27.675 us; speedup 1.0000x reference)
//
#include <hip/hip_runtime.h>

// TransientGenerator — grid-stride gather, 2048 blocks (8/CU), ~5 chunks/block.
// Metadata staged ONCE per block (one barrier per block life); sorted start
// times cached in 4 regs/lane for per-chunk ballots; successive chunks have
// no barriers between them so their load/FMA/store streams pipeline.

constexpr int SR    = 16000;  // SAMPLE_RATE
constexpr int TL    = 1600;   // TRANSIENT_SAMPLES
constexpr int MAXT  = 256;    // MAX_TRANSIENTS (== blockDim)
constexpr int NTHR  = 256;
constexpr int CHUNK = 1024;   // NTHR * 4 samples per chunk
constexpr int BPB   = 32;     // blocks per batch  (grid = 64 * 32 = 2048 = 8/CU)

__global__ __launch_bounds__(NTHR, 8)
void transient_gs(const float* __restrict__ timings,   // [B,T]
                  const int*   __restrict__ ids,       // [B,T]
                  const float* __restrict__ gains,     // [B,T]
                  const float* __restrict__ templates, // [n_tr,TL]
                  float*       __restrict__ out,       // [B,A]
                  int T, int n_tr, int A, int nchunk)
{
    __shared__ int2 s_m [MAXT];   // (ts<<8)|id , gain bits (0 if invalid)
    __shared__ int  s_ts[MAXT];   // clamped start sample (sorted)

    const int b    = blockIdx.y;
    const int tid  = (int)threadIdx.x;
    const int lane = tid & 63;

    {   // stage transient j = tid once per block (T == NTHR)
        const float tm = timings[(size_t)b * T + tid];
        const float g  = gains  [(size_t)b * T + tid];
        const int   id = ids    [(size_t)b * T + tid];
        const int   ts = (int)floorf(tm * (float)SR);   // matches jnp.floor(t*SR) fp32
        const bool ok  = (g > 0.0f) & (id < n_tr) & (ts < A);
        const int tsc  = min(max(ts, 0), A);            // clamp preserves sorted order
        const int idc  = min(max(id, 0), n_tr - 1);
        s_m [tid] = make_int2((tsc << 8) | idc, ok ? __float_as_int(g) : 0);
        s_ts[tid] = tsc;
    }
    __syncthreads();                                    // the ONLY barrier in the kernel

    // cache all 256 sorted start times: 4 per lane, for in-register ballots
    int tsr[4];
#pragma unroll
    for (int q = 0; q < 4; ++q) tsr[q] = s_ts[q * 64 + lane];

    for (int c = blockIdx.x; c < nchunk; c += BPB) {    // ~5 chunks per block
        const int chunk0 = c * CHUNK;

        // overlap interval [lo,hi] via 4 ballots (sorted ts => interval)
        int lo = T, hi = -1;
#pragma unroll
        for (int q = 0; q < 4; ++q) {
            const bool ov = (tsr[q] < chunk0 + CHUNK) & (tsr[q] + TL > chunk0);
            const unsigned long long m = __ballot(ov);
            if (m) {
                lo = min(lo, q * 64 + (int)__builtin_ctzll(m));
                hi = max(hi, q * 64 + 63 - (int)__builtin_clzll(m));
            }
        }

        float acc[4] = {0.f, 0.f, 0.f, 0.f};
        const int off_base = chunk0 + tid;

        for (int j = lo; j <= hi; ++j) {                // iterations independent
            const int2 mj  = s_m[j];                    // broadcast ds_read_b64
            const int  mx  = __builtin_amdgcn_readfirstlane(mj.x);
            const int  mgb = __builtin_amdgcn_readfirstlane(mj.y);
            if (mgb == 0) continue;                     // uniform skip (invalid)
            const float g  = __int_as_float(mgb);
            const int   ts = mx >> 8;
            const float* __restrict__ row = templates + (size_t)(mx & 255) * TL;
            const int off0 = off_base - ts;
#pragma unroll
            for (int k = 0; k < 4; ++k) {
                const int o = off0 + k * NTHR;
                if ((unsigned)o < (unsigned)TL)         // exec-masked, lane-consecutive
                    acc[k] += g * row[o];
            }
        }

        float* ob = out + (size_t)b * A + off_base;
#pragma unroll
        for (int k = 0; k < 4; ++k) {
            if (off_base + k * NTHR < A)
                __builtin_nontemporal_store(acc[k], &ob[k * NTHR]);
        }
    }
}

extern "C" void kernel_launch(void* const* d_in, const int* in_sizes, int n_in,
                              void* d_out, int out_size, void* d_ws, size_t ws_size,
                              hipStream_t stream) {
    const float* timings   = (const float*)d_in[0];
    const int*   ids       = (const int*)  d_in[1];
    const float* gains     = (const float*)d_in[2];
    const float* templates = (const float*)d_in[3];
    float*       out       = (float*)d_out;

    const int T      = MAXT;               // reference MAX_TRANSIENTS
    const int B      = in_sizes[0] / T;
    const int n_tr   = in_sizes[3] / TL;   // templates are [n_tr, TL]
    const int A      = out_size / B;       // audio_length
    const int nchunk = (A + CHUNK - 1) / CHUNK;

    dim3 grid(BPB, B), block(NTHR);
    transient_gs<<<grid, block, 0, stream>>>(timings, ids, gains, templates, out,
                                             T, n_tr, A, nchunk);
}